// Round 10
// baseline (54.783 us; speedup 1.0000x reference)
//
#include <hip/hip_runtime.h>
#include <hip/hip_bf16.h>

#define KDIM  1024
#define NOUT  1024
#define NTOK  8192
#define NCB   16
#define BM    64
#define BN    128
#define BK    32
#define TILEB 12288   // bytes per K-tile buffer: A 4KB + B 8KB
#define NBUF  3

typedef __attribute__((ext_vector_type(8))) short short8;
typedef __attribute__((ext_vector_type(4))) float f32x4;

__device__ static inline unsigned short f2bf(float f) {
    unsigned int u = __float_as_uint(f);
    return (unsigned short)((u + 0x7FFFu + ((u >> 16) & 1u)) >> 16);
}

__device__ static inline float bf2f(unsigned int h) {
    return __uint_as_float(h << 16);
}

__device__ static inline void async_copy16(const void* g, void* l) {
    __builtin_amdgcn_global_load_lds(
        (const __attribute__((address_space(1))) void*)g,
        (__attribute__((address_space(3))) void*)l, 16, 0, 0);
}

// ---- combined convert: blocks [0,4096) do x->A (XCD-aligned), rest W->Bt ----
__global__ __launch_bounds__(256) void conv_kernel(const float* __restrict__ x,
                                                   const float* __restrict__ W,
                                                   unsigned short* __restrict__ A,
                                                   unsigned short* __restrict__ Bt) {
    int b = blockIdx.x;
    if (b < 4096) {
        // remap so token-panel p = t/1024 is produced on XCD p (matches gemm/epilogue)
        int bb = (b & 7) * 512 + (b >> 3);
        int u = bb * 256 + threadIdx.x;
        const float* src = x + (size_t)u * 8;
        float4 v0 = *(const float4*)(src);
        float4 v1 = *(const float4*)(src + 4);
        short8 o;
        o[0] = (short)f2bf(v0.x); o[1] = (short)f2bf(v0.y);
        o[2] = (short)f2bf(v0.z); o[3] = (short)f2bf(v0.w);
        o[4] = (short)f2bf(v1.x); o[5] = (short)f2bf(v1.y);
        o[6] = (short)f2bf(v1.z); o[7] = (short)f2bf(v1.w);
        *(short8*)(A + (size_t)u * 8) = o;
    } else {
        int u = (b - 4096) * 256 + threadIdx.x;
        int n  = u & (NOUT - 1);
        int k0 = (u >> 10) << 3;
        int h = n >> 6, o = n & 63;
        const float* src = W + (size_t)h * KDIM * 64 + o;
        short8 v;
#pragma unroll
        for (int j = 0; j < 8; ++j)
            v[j] = (short)f2bf(src[(size_t)(k0 + j) * 64]);
        *(short8*)(Bt + (size_t)n * KDIM + k0) = v;
    }
}

// stage one K-tile: A 64x32 bf16 (4KB, 2 slots/thread) + B 128x32 (8KB, 4/thread),
// all linear (uniform 8 dwords/bank on frag reads -> conflict-free, verified R8/R9).
__device__ __forceinline__ void stage_tile(const unsigned short* __restrict__ A,
                                           const unsigned short* __restrict__ Bt,
                                           char* lbase, int tid, int m0, int n0, int kel) {
    unsigned short* Al = (unsigned short*)lbase;
    unsigned short* Bl = (unsigned short*)(lbase + 4096);
#pragma unroll
    for (int i = 0; i < 2; ++i) {
        int s = i * 128 + tid;          // 16B slot, 0..255
        int row = s >> 2, c = s & 3;
        async_copy16(A + (size_t)(m0 + row) * KDIM + kel + c * 8, Al + s * 8);
    }
#pragma unroll
    for (int i = 0; i < 4; ++i) {
        int s = i * 128 + tid;          // 0..511
        int row = s >> 2, c = s & 3;
        async_copy16(Bt + (size_t)(n0 + row) * KDIM + kel + c * 8, Bl + s * 8);
    }
}

// one pipelined K-step: stage(kt+2) -> vmcnt(VM) -> bar -> ds_read frags ->
// lgkmcnt(0) -> bar -> setprio(1) 16 MFMA setprio(0).  6 loads/thread/tile;
// steady VM=12 keeps tiles kt+1,kt+2 in flight; never drains to 0 mid-loop.
template <int VM, bool STAGE>
__device__ __forceinline__ void gemm_step(const unsigned short* __restrict__ A,
                                          const unsigned short* __restrict__ Bt,
                                          char* lds, int tid, int m0, int n0, int kt,
                                          int wc, int r15, int q,
                                          f32x4 (&acc)[4][4]) {
    if (STAGE)
        stage_tile(A, Bt, lds + ((kt + 2) % NBUF) * TILEB, tid, m0, n0, (kt + 2) * BK);
    asm volatile("s_waitcnt vmcnt(%0)" :: "i"(VM) : "memory");
    __builtin_amdgcn_sched_barrier(0);
    __builtin_amdgcn_s_barrier();

    const unsigned short* Al = (const unsigned short*)(lds + (kt % NBUF) * TILEB);
    const unsigned short* Bl = Al + 2048;
    const int kq = q * 8;
    short8 af[4], bf[4];
#pragma unroll
    for (int mf = 0; mf < 4; ++mf)
        af[mf] = *(const short8*)(Al + (mf * 16 + r15) * 32 + kq);
#pragma unroll
    for (int nf = 0; nf < 4; ++nf)
        bf[nf] = *(const short8*)(Bl + (wc + nf * 16 + r15) * 32 + kq);

    asm volatile("s_waitcnt lgkmcnt(0)" ::: "memory");
    __builtin_amdgcn_sched_barrier(0);
    __builtin_amdgcn_s_barrier();   // buffer (kt)%NBUF reusable by stage at kt+1

    __builtin_amdgcn_s_setprio(1);
#pragma unroll
    for (int mf = 0; mf < 4; ++mf)
#pragma unroll
        for (int nf = 0; nf < 4; ++nf)
            acc[mf][nf] = __builtin_amdgcn_mfma_f32_16x16x32_bf16(af[mf], bf[nf], acc[mf][nf], 0, 0, 0);
    __builtin_amdgcn_s_setprio(0);
}

// ---- GEMM: Y[m][n] = sum_k A[m][k]*Bt[n][k]; BM=64 BN=128, 2 waves (1x2),
// 1024 blocks = 4 blocks/CU (m97 occupancy), 3-buffer counted-vmcnt pipeline,
// XCD remap: XCD owns m-panels [xcd*16,xcd*16+16) x all n (A 2MB + Bt 2MB in L2).
__global__ __launch_bounds__(128, 2) void gemm_kernel(const unsigned short* __restrict__ A,
                                                      const unsigned short* __restrict__ Bt,
                                                      unsigned short* __restrict__ Y) {
    extern __shared__ char lds[];   // 3 * 12KB

    const int id  = blockIdx.x;
    const int xcd = id & 7;
    const int j   = id >> 3;                  // 0..127
    const int m0  = (xcd * 16 + (j >> 3)) * BM;
    const int n0  = (j & 7) * BN;

    const int tid  = threadIdx.x;
    const int lane = tid & 63;
    const int w    = tid >> 6;                // 0..1
    const int wc   = w * 64;
    const int r15  = lane & 15;
    const int q    = lane >> 4;

    f32x4 acc[4][4];
#pragma unroll
    for (int mf = 0; mf < 4; ++mf)
#pragma unroll
        for (int nf = 0; nf < 4; ++nf)
            acc[mf][nf] = (f32x4){0.f, 0.f, 0.f, 0.f};

    // prologue: tiles 0 and 1 in flight
    stage_tile(A, Bt, lds,         tid, m0, n0, 0);
    stage_tile(A, Bt, lds + TILEB, tid, m0, n0, BK);

#pragma unroll 2
    for (int kt = 0; kt < 30; ++kt)
        gemm_step<12, true>(A, Bt, lds, tid, m0, n0, kt, wc, r15, q, acc);
    gemm_step<6, false>(A, Bt, lds, tid, m0, n0, 30, wc, r15, q, acc);
    gemm_step<0, false>(A, Bt, lds, tid, m0, n0, 31, wc, r15, q, acc);

    // write back: D layout col=lane&15, row=(lane>>4)*4+r
#pragma unroll
    for (int mf = 0; mf < 4; ++mf)
#pragma unroll
        for (int nf = 0; nf < 4; ++nf) {
            int col = n0 + wc + nf * 16 + r15;
#pragma unroll
            for (int r = 0; r < 4; ++r) {
                int row = m0 + mf * 16 + q * 4 + r;
                Y[(size_t)row * NOUT + col] = f2bf(acc[mf][nf][r]);
            }
        }
}

// ---- epilogue: outer product + mean*sqrt(h) + rms_norm; 1 block/token,
// XCD-aligned so Y reads hit the L2 of the XCD that produced them. ----
__global__ __launch_bounds__(256) void epilogue_kernel(const unsigned short* __restrict__ Y,
                                                       float* __restrict__ out) {
    __shared__ float ylds[1024];
    __shared__ float red[4];

    const int t = (blockIdx.x & 7) * 1024 + (blockIdx.x >> 3);
    const int tid = threadIdx.x;
    const unsigned short* yrow = Y + (size_t)t * NOUT;

    {
        uint2 raw = *(const uint2*)(yrow + tid * 4);
        ylds[tid * 4 + 0] = bf2f(raw.x & 0xffffu);
        ylds[tid * 4 + 1] = bf2f(raw.x >> 16);
        ylds[tid * 4 + 2] = bf2f(raw.y & 0xffffu);
        ylds[tid * 4 + 3] = bf2f(raw.y >> 16);
    }
    __syncthreads();

    const int jj = tid >> 3;
    const int k0 = (tid & 7) * 4;

    float o0 = 0.f, o1 = 0.f, o2 = 0.f, o3 = 0.f;
#pragma unroll
    for (int h = 0; h < NCB; ++h) {
        float a = ylds[h * 64 + jj];
        float4 bb = *(const float4*)&ylds[h * 64 + 32 + k0];
        o0 += a * bb.x; o1 += a * bb.y; o2 += a * bb.z; o3 += a * bb.w;
    }
    o0 *= 0.25f; o1 *= 0.25f; o2 *= 0.25f; o3 *= 0.25f;

    float ss = o0 * o0 + o1 * o1 + o2 * o2 + o3 * o3;
#pragma unroll
    for (int off = 32; off >= 1; off >>= 1)
        ss += __shfl_xor(ss, off, 64);

    const int lane = tid & 63, wv = tid >> 6;
    if (lane == 0) red[wv] = ss;
    __syncthreads();
    float tot = red[0] + red[1] + red[2] + red[3];
    float scale = rsqrtf(tot * (1.0f / 1024.0f) + 1e-12f);

    float4 o;
    o.x = o0 * scale; o.y = o1 * scale; o.z = o2 * scale; o.w = o3 * scale;
    *(float4*)(out + (size_t)t * 1024 + tid * 4) = o;
}

extern "C" void kernel_launch(void* const* d_in, const int* in_sizes, int n_in,
                              void* d_out, int out_size, void* d_ws, size_t ws_size,
                              hipStream_t stream) {
    const float* x   = (const float*)d_in[0];
    const float* wgt = (const float*)d_in[1];
    float* out = (float*)d_out;

    unsigned short* A  = (unsigned short*)d_ws;                        // 16 MB
    unsigned short* Bt = (unsigned short*)((char*)d_ws + (16u << 20)); //  2 MB
    unsigned short* Y  = (unsigned short*)((char*)d_ws + (18u << 20)); // 16 MB

    (void)hipFuncSetAttribute((const void*)gemm_kernel,
                              hipFuncAttributeMaxDynamicSharedMemorySize, NBUF * TILEB);

    conv_kernel<<<4096 + 512, 256, 0, stream>>>(x, wgt, A, Bt);
    gemm_kernel<<<(NTOK / BM) * (NOUT / BN), 128, NBUF * TILEB, stream>>>(A, Bt, Y);
    epilogue_kernel<<<NTOK, 256, 0, stream>>>(Y, out);
}

// Round 11
// 48.396 us; speedup vs baseline: 1.1320x; 1.1320x over previous
//
#include <hip/hip_runtime.h>
#include <hip/hip_bf16.h>

#define KDIM  1024
#define NOUT  1024
#define NTOK  8192
#define NCB   16
#define BM    256
#define BN    128
#define BK    64
#define TILEB 49152   // A 32KB + B 16KB per K-tile buffer
#define NBUF  3

typedef __attribute__((ext_vector_type(8))) short short8;
typedef __attribute__((ext_vector_type(4))) float f32x4;

__device__ static inline unsigned short f2bf(float f) {
    unsigned int u = __float_as_uint(f);
    return (unsigned short)((u + 0x7FFFu + ((u >> 16) & 1u)) >> 16);
}

__device__ static inline float bf2f(unsigned int h) {
    return __uint_as_float(h << 16);
}

__device__ static inline void async_copy16(const void* g, void* l) {
    __builtin_amdgcn_global_load_lds(
        (const __attribute__((address_space(1))) void*)g,
        (__attribute__((address_space(3))) void*)l, 16, 0, 0);
}

// ---- combined convert: blocks [0,4096) do x->A, [4096,4608) do W->Bt ----
__global__ __launch_bounds__(256) void conv_kernel(const float* __restrict__ x,
                                                   const float* __restrict__ W,
                                                   unsigned short* __restrict__ A,
                                                   unsigned short* __restrict__ Bt) {
    int b = blockIdx.x;
    if (b < 4096) {
        int u = b * 256 + threadIdx.x;
        const float* src = x + (size_t)u * 8;
        float4 v0 = *(const float4*)(src);
        float4 v1 = *(const float4*)(src + 4);
        short8 o;
        o[0] = (short)f2bf(v0.x); o[1] = (short)f2bf(v0.y);
        o[2] = (short)f2bf(v0.z); o[3] = (short)f2bf(v0.w);
        o[4] = (short)f2bf(v1.x); o[5] = (short)f2bf(v1.y);
        o[6] = (short)f2bf(v1.z); o[7] = (short)f2bf(v1.w);
        *(short8*)(A + (size_t)u * 8) = o;
    } else {
        int u = (b - 4096) * 256 + threadIdx.x;
        int n  = u & (NOUT - 1);
        int k0 = (u >> 10) << 3;
        int h = n >> 6, o = n & 63;
        const float* src = W + (size_t)h * KDIM * 64 + o;
        short8 v;
#pragma unroll
        for (int j = 0; j < 8; ++j)
            v[j] = (short)f2bf(src[(size_t)(k0 + j) * 64]);
        *(short8*)(Bt + (size_t)n * KDIM + k0) = v;
    }
}

// ---- GEMM, R6 geometry with m201-style 2-phase K-tile split ----
// BM=256 BN=128 BK=64, 512 thr (8 waves, 4M x 2N, 64x64/wave), NBUF=3.
// XOR chunk-swizzle ch^=(row&7) over 128B rows (8-dw/bank uniform, verified R6).
// Per phase: barrier -> stage 3 gloads(t+2) -> 8 ds_read(kk) -> lgkm0 -> 16 MFMA.
// vmcnt(6) once per tile (t+1's 6 loads stay in flight) - never drains mid-loop.

template <int VM, bool STAGE>
__device__ __forceinline__ void phase0(const unsigned short* __restrict__ A,
                                       const unsigned short* __restrict__ Bt,
                                       char* lds, int tid, int m0, int n0, int kt,
                                       int wm, int wn, int r15, int q,
                                       f32x4 (&acc)[4][4]) {
    asm volatile("s_waitcnt vmcnt(%0)" :: "i"(VM) : "memory");
    __builtin_amdgcn_sched_barrier(0);
    __builtin_amdgcn_s_barrier();
    __builtin_amdgcn_sched_barrier(0);
    if (STAGE) {
        char* lb = lds + ((kt + 2) % NBUF) * TILEB;
        unsigned short* Als = (unsigned short*)lb;
        unsigned short* Bls = (unsigned short*)(lb + 32768);
        const int kel = (kt + 2) * BK;
#pragma unroll
        for (int i = 0; i < 2; ++i) {
            int s = i * 512 + tid;
            int row = s >> 3;
            int cs = (s & 7) ^ (row & 7);
            async_copy16(A + (size_t)(m0 + row) * KDIM + kel + cs * 8, Als + s * 8);
        }
        {
            int s = tid;
            int row = s >> 3;
            int cs = (s & 7) ^ (row & 7);
            async_copy16(Bt + (size_t)(n0 + row) * KDIM + kel + cs * 8, Bls + s * 8);
        }
    }
    const unsigned short* Al = (const unsigned short*)(lds + (kt % NBUF) * TILEB);
    const unsigned short* Bl = Al + 16384;
    short8 af[4], bf[4];
#pragma unroll
    for (int mf = 0; mf < 4; ++mf) {
        int row = wm * 64 + mf * 16 + r15;
        af[mf] = *(const short8*)(Al + row * 64 + ((q ^ (row & 7)) << 3));
    }
#pragma unroll
    for (int nf = 0; nf < 4; ++nf) {
        int row = wn * 64 + nf * 16 + r15;
        bf[nf] = *(const short8*)(Bl + row * 64 + ((q ^ (row & 7)) << 3));
    }
    asm volatile("s_waitcnt lgkmcnt(0)" ::: "memory");
    __builtin_amdgcn_sched_barrier(0);
    __builtin_amdgcn_s_setprio(1);
#pragma unroll
    for (int mf = 0; mf < 4; ++mf)
#pragma unroll
        for (int nf = 0; nf < 4; ++nf)
            acc[mf][nf] = __builtin_amdgcn_mfma_f32_16x16x32_bf16(af[mf], bf[nf], acc[mf][nf], 0, 0, 0);
    __builtin_amdgcn_s_setprio(0);
}

template <bool STAGE>
__device__ __forceinline__ void phase1(const unsigned short* __restrict__ A,
                                       const unsigned short* __restrict__ Bt,
                                       char* lds, int tid, int m0, int n0, int kt,
                                       int wm, int wn, int r15, int q,
                                       f32x4 (&acc)[4][4]) {
    __builtin_amdgcn_s_barrier();
    __builtin_amdgcn_sched_barrier(0);
    if (STAGE) {
        char* lb = lds + ((kt + 2) % NBUF) * TILEB;
        unsigned short* Als = (unsigned short*)lb;
        unsigned short* Bls = (unsigned short*)(lb + 32768);
        const int kel = (kt + 2) * BK;
#pragma unroll
        for (int i = 2; i < 4; ++i) {
            int s = i * 512 + tid;
            int row = s >> 3;
            int cs = (s & 7) ^ (row & 7);
            async_copy16(A + (size_t)(m0 + row) * KDIM + kel + cs * 8, Als + s * 8);
        }
        {
            int s = 512 + tid;
            int row = s >> 3;
            int cs = (s & 7) ^ (row & 7);
            async_copy16(Bt + (size_t)(n0 + row) * KDIM + kel + cs * 8, Bls + s * 8);
        }
    }
    const unsigned short* Al = (const unsigned short*)(lds + (kt % NBUF) * TILEB);
    const unsigned short* Bl = Al + 16384;
    short8 af[4], bf[4];
#pragma unroll
    for (int mf = 0; mf < 4; ++mf) {
        int row = wm * 64 + mf * 16 + r15;
        af[mf] = *(const short8*)(Al + row * 64 + (((4 + q) ^ (row & 7)) << 3));
    }
#pragma unroll
    for (int nf = 0; nf < 4; ++nf) {
        int row = wn * 64 + nf * 16 + r15;
        bf[nf] = *(const short8*)(Bl + row * 64 + (((4 + q) ^ (row & 7)) << 3));
    }
    asm volatile("s_waitcnt lgkmcnt(0)" ::: "memory");
    __builtin_amdgcn_sched_barrier(0);
    __builtin_amdgcn_s_setprio(1);
#pragma unroll
    for (int mf = 0; mf < 4; ++mf)
#pragma unroll
        for (int nf = 0; nf < 4; ++nf)
            acc[mf][nf] = __builtin_amdgcn_mfma_f32_16x16x32_bf16(af[mf], bf[nf], acc[mf][nf], 0, 0, 0);
    __builtin_amdgcn_s_setprio(0);
}

// full-tile prologue stage (6 loads)
__device__ __forceinline__ void stage_full(const unsigned short* __restrict__ A,
                                           const unsigned short* __restrict__ Bt,
                                           char* lbase, int tid, int m0, int n0, int kel) {
    unsigned short* Als = (unsigned short*)lbase;
    unsigned short* Bls = (unsigned short*)(lbase + 32768);
#pragma unroll
    for (int i = 0; i < 4; ++i) {
        int s = i * 512 + tid;
        int row = s >> 3;
        int cs = (s & 7) ^ (row & 7);
        async_copy16(A + (size_t)(m0 + row) * KDIM + kel + cs * 8, Als + s * 8);
    }
#pragma unroll
    for (int i = 0; i < 2; ++i) {
        int s = i * 512 + tid;
        int row = s >> 3;
        int cs = (s & 7) ^ (row & 7);
        async_copy16(Bt + (size_t)(n0 + row) * KDIM + kel + cs * 8, Bls + s * 8);
    }
}

__global__ __launch_bounds__(512, 2) void gemm_kernel(const unsigned short* __restrict__ A,
                                                      const unsigned short* __restrict__ Bt,
                                                      unsigned short* __restrict__ Y) {
    extern __shared__ char lds[];   // 3 * 48KB

    const int id  = blockIdx.x;
    const int xcd = id & 7;
    const int j   = id >> 3;                  // 0..31
    const int m0  = (xcd * 4 + (j >> 3)) * BM;
    const int n0  = (j & 7) * BN;

    const int tid  = threadIdx.x;
    const int lane = tid & 63;
    const int w    = tid >> 6;
    const int wm   = w >> 1;
    const int wn   = w & 1;
    const int r15  = lane & 15;
    const int q    = lane >> 4;

    f32x4 acc[4][4];
#pragma unroll
    for (int mf = 0; mf < 4; ++mf)
#pragma unroll
        for (int nf = 0; nf < 4; ++nf)
            acc[mf][nf] = (f32x4){0.f, 0.f, 0.f, 0.f};

    stage_full(A, Bt, lds,         tid, m0, n0, 0);
    stage_full(A, Bt, lds + TILEB, tid, m0, n0, BK);

#pragma unroll 1
    for (int kt = 0; kt < 14; ++kt) {
        phase0<6, true>(A, Bt, lds, tid, m0, n0, kt, wm, wn, r15, q, acc);
        phase1<true>   (A, Bt, lds, tid, m0, n0, kt, wm, wn, r15, q, acc);
    }
    phase0<6, false>(A, Bt, lds, tid, m0, n0, 14, wm, wn, r15, q, acc);
    phase1<false>   (A, Bt, lds, tid, m0, n0, 14, wm, wn, r15, q, acc);
    phase0<0, false>(A, Bt, lds, tid, m0, n0, 15, wm, wn, r15, q, acc);
    phase1<false>   (A, Bt, lds, tid, m0, n0, 15, wm, wn, r15, q, acc);

    // write back: D layout col=lane&15, row=(lane>>4)*4+r
#pragma unroll
    for (int mf = 0; mf < 4; ++mf)
#pragma unroll
        for (int nf = 0; nf < 4; ++nf) {
            int col = n0 + wn * 64 + nf * 16 + r15;
#pragma unroll
            for (int r = 0; r < 4; ++r) {
                int row = m0 + wm * 64 + mf * 16 + q * 4 + r;
                Y[(size_t)row * NOUT + col] = f2bf(acc[mf][nf][r]);
            }
        }
}

// ---- epilogue: outer product + mean*sqrt(h) + rms_norm; 1 block/token ----
__global__ __launch_bounds__(256) void epilogue_kernel(const unsigned short* __restrict__ Y,
                                                       float* __restrict__ out) {
    __shared__ float ylds[1024];
    __shared__ float red[4];

    const int t = blockIdx.x;
    const int tid = threadIdx.x;
    const unsigned short* yrow = Y + (size_t)t * NOUT;

    {
        uint2 raw = *(const uint2*)(yrow + tid * 4);
        ylds[tid * 4 + 0] = bf2f(raw.x & 0xffffu);
        ylds[tid * 4 + 1] = bf2f(raw.x >> 16);
        ylds[tid * 4 + 2] = bf2f(raw.y & 0xffffu);
        ylds[tid * 4 + 3] = bf2f(raw.y >> 16);
    }
    __syncthreads();

    const int jj = tid >> 3;
    const int k0 = (tid & 7) * 4;

    float o0 = 0.f, o1 = 0.f, o2 = 0.f, o3 = 0.f;
#pragma unroll
    for (int h = 0; h < NCB; ++h) {
        float a = ylds[h * 64 + jj];
        float4 bb = *(const float4*)&ylds[h * 64 + 32 + k0];
        o0 += a * bb.x; o1 += a * bb.y; o2 += a * bb.z; o3 += a * bb.w;
    }
    o0 *= 0.25f; o1 *= 0.25f; o2 *= 0.25f; o3 *= 0.25f;

    float ss = o0 * o0 + o1 * o1 + o2 * o2 + o3 * o3;
#pragma unroll
    for (int off = 32; off >= 1; off >>= 1)
        ss += __shfl_xor(ss, off, 64);

    const int lane = tid & 63, wv = tid >> 6;
    if (lane == 0) red[wv] = ss;
    __syncthreads();
    float tot = red[0] + red[1] + red[2] + red[3];
    float scale = rsqrtf(tot * (1.0f / 1024.0f) + 1e-12f);

    float4 o;
    o.x = o0 * scale; o.y = o1 * scale; o.z = o2 * scale; o.w = o3 * scale;
    *(float4*)(out + (size_t)t * 1024 + tid * 4) = o;
}

extern "C" void kernel_launch(void* const* d_in, const int* in_sizes, int n_in,
                              void* d_out, int out_size, void* d_ws, size_t ws_size,
                              hipStream_t stream) {
    const float* x   = (const float*)d_in[0];
    const float* wgt = (const float*)d_in[1];
    float* out = (float*)d_out;

    unsigned short* A  = (unsigned short*)d_ws;                        // 16 MB
    unsigned short* Bt = (unsigned short*)((char*)d_ws + (16u << 20)); //  2 MB
    unsigned short* Y  = (unsigned short*)((char*)d_ws + (18u << 20)); // 16 MB

    (void)hipFuncSetAttribute((const void*)gemm_kernel,
                              hipFuncAttributeMaxDynamicSharedMemorySize, NBUF * TILEB);

    conv_kernel<<<4096 + 512, 256, 0, stream>>>(x, wgt, A, Bt);
    gemm_kernel<<<(NTOK / BM) * (NOUT / BN), 512, NBUF * TILEB, stream>>>(A, Bt, Y);
    epilogue_kernel<<<NTOK, 256, 0, stream>>>(Y, out);
}

// Round 12
// 47.589 us; speedup vs baseline: 1.1512x; 1.0170x over previous
//
#include <hip/hip_runtime.h>
#include <hip/hip_bf16.h>

#define KDIM  1024
#define NOUT  1024
#define NTOK  8192
#define NCB   16
#define BM    256
#define BN    128
#define BK    64
#define TILEB 49152   // A 32KB + B 16KB per K-tile buffer
#define NBUF  3

typedef __attribute__((ext_vector_type(8))) short short8;
typedef __attribute__((ext_vector_type(4))) float f32x4;

__device__ static inline unsigned short f2bf(float f) {
    unsigned int u = __float_as_uint(f);
    return (unsigned short)((u + 0x7FFFu + ((u >> 16) & 1u)) >> 16);
}

__device__ static inline float bf2f(unsigned int h) {
    return __uint_as_float(h << 16);
}

__device__ static inline void async_copy16(const void* g, void* l) {
    __builtin_amdgcn_global_load_lds(
        (const __attribute__((address_space(1))) void*)g,
        (__attribute__((address_space(3))) void*)l, 16, 0, 0);
}

// ---- combined convert: x->A (XCD-aligned with gemm m-panels), W->Bt ----
__global__ __launch_bounds__(256) void conv_kernel(const float* __restrict__ x,
                                                   const float* __restrict__ W,
                                                   unsigned short* __restrict__ A,
                                                   unsigned short* __restrict__ Bt) {
    int b = blockIdx.x;
    if (b < 4096) {
        int bb = (b & 7) * 512 + (b >> 3);   // token-panel p -> XCD p (matches gemm)
        int u = bb * 256 + threadIdx.x;
        const float* src = x + (size_t)u * 8;
        float4 v0 = *(const float4*)(src);
        float4 v1 = *(const float4*)(src + 4);
        short8 o;
        o[0] = (short)f2bf(v0.x); o[1] = (short)f2bf(v0.y);
        o[2] = (short)f2bf(v0.z); o[3] = (short)f2bf(v0.w);
        o[4] = (short)f2bf(v1.x); o[5] = (short)f2bf(v1.y);
        o[6] = (short)f2bf(v1.z); o[7] = (short)f2bf(v1.w);
        *(short8*)(A + (size_t)u * 8) = o;
    } else {
        int u = (b - 4096) * 256 + threadIdx.x;
        int n  = u & (NOUT - 1);
        int k0 = (u >> 10) << 3;
        int h = n >> 6, o = n & 63;
        const float* src = W + (size_t)h * KDIM * 64 + o;
        short8 v;
#pragma unroll
        for (int j = 0; j < 8; ++j)
            v[j] = (short)f2bf(src[(size_t)(k0 + j) * 64]);
        *(short8*)(Bt + (size_t)n * KDIM + k0) = v;
    }
}

// ---- GEMM: R11 geometry + m201-style register frag-prefetch ----
// BM=256 BN=128 BK=64, 512 thr (8 waves 4Mx2N, 64x64/wave), NBUF=3.
// Each phase issues NEXT half-tile's 8 ds_reads, waits lgkmcnt(8) (retires the
// PREVIOUS issue), then 16 MFMA -> ds latency hidden under MFMA within-wave.

__device__ __forceinline__ void stage_half(const unsigned short* __restrict__ A,
                                           const unsigned short* __restrict__ Bt,
                                           char* lbase, int tid, int m0, int n0,
                                           int kel, int half) {
    unsigned short* Als = (unsigned short*)lbase;
    unsigned short* Bls = (unsigned short*)(lbase + 32768);
#pragma unroll
    for (int i = 0; i < 2; ++i) {
        int s = (half * 2 + i) * 512 + tid;
        int row = s >> 3;
        int cs = (s & 7) ^ (row & 7);
        async_copy16(A + (size_t)(m0 + row) * KDIM + kel + cs * 8, Als + s * 8);
    }
    {
        int s = half * 512 + tid;
        int row = s >> 3;
        int cs = (s & 7) ^ (row & 7);
        async_copy16(Bt + (size_t)(n0 + row) * KDIM + kel + cs * 8, Bls + s * 8);
    }
}

__device__ __forceinline__ void read_frags(const char* lds, int buf, int chunk,
                                           int wm, int wn, int r15, int q,
                                           short8 (&af)[4], short8 (&bf)[4]) {
    const unsigned short* Al = (const unsigned short*)(lds + buf * TILEB);
    const unsigned short* Bl = Al + 16384;
#pragma unroll
    for (int mf = 0; mf < 4; ++mf) {
        int row = wm * 64 + mf * 16 + r15;
        af[mf] = *(const short8*)(Al + row * 64 + (((chunk + q) ^ (row & 7)) << 3));
    }
#pragma unroll
    for (int nf = 0; nf < 4; ++nf) {
        int row = wn * 64 + nf * 16 + r15;
        bf[nf] = *(const short8*)(Bl + row * 64 + (((chunk + q) ^ (row & 7)) << 3));
    }
}

__device__ __forceinline__ void mfma16(short8 (&af)[4], short8 (&bf)[4], f32x4 (&acc)[4][4]) {
    __builtin_amdgcn_s_setprio(1);
#pragma unroll
    for (int mf = 0; mf < 4; ++mf)
#pragma unroll
        for (int nf = 0; nf < 4; ++nf)
            acc[mf][nf] = __builtin_amdgcn_mfma_f32_16x16x32_bf16(af[mf], bf[nf], acc[mf][nf], 0, 0, 0);
    __builtin_amdgcn_s_setprio(0);
}

// phase0(t): vmcnt(VM); bar; stage half0(t+2); prefetch half1(t) -> Fn;
//            lgkmcnt(8); MFMA half0(t) from Fc.
template <int VM, bool STAGE>
__device__ __forceinline__ void phase0(const unsigned short* __restrict__ A,
                                       const unsigned short* __restrict__ Bt,
                                       char* lds, int tid, int m0, int n0, int kt,
                                       int wm, int wn, int r15, int q,
                                       short8 (&afc)[4], short8 (&bfc)[4],
                                       short8 (&afn)[4], short8 (&bfn)[4],
                                       f32x4 (&acc)[4][4]) {
    asm volatile("s_waitcnt vmcnt(%0)" :: "i"(VM) : "memory");
    __builtin_amdgcn_sched_barrier(0);
    __builtin_amdgcn_s_barrier();
    __builtin_amdgcn_sched_barrier(0);
    if (STAGE)
        stage_half(A, Bt, lds + ((kt + 2) % NBUF) * TILEB, tid, m0, n0, (kt + 2) * BK, 0);
    read_frags(lds, kt % NBUF, 4, wm, wn, r15, q, afn, bfn);   // half1(t)
    asm volatile("s_waitcnt lgkmcnt(8)" ::: "memory");
    __builtin_amdgcn_sched_barrier(0);
    mfma16(afc, bfc, acc);
}

// phase1(t): vmcnt(VM) [t+1 landed]; bar; stage half1(t+2);
//            prefetch half0(t+1) -> Fn; lgkmcnt(8 or 0); MFMA half1(t) from Fc.
template <int VM, bool STAGE, bool PRE>
__device__ __forceinline__ void phase1(const unsigned short* __restrict__ A,
                                       const unsigned short* __restrict__ Bt,
                                       char* lds, int tid, int m0, int n0, int kt,
                                       int wm, int wn, int r15, int q,
                                       short8 (&afc)[4], short8 (&bfc)[4],
                                       short8 (&afn)[4], short8 (&bfn)[4],
                                       f32x4 (&acc)[4][4]) {
    asm volatile("s_waitcnt vmcnt(%0)" :: "i"(VM) : "memory");
    __builtin_amdgcn_sched_barrier(0);
    __builtin_amdgcn_s_barrier();
    __builtin_amdgcn_sched_barrier(0);
    if (STAGE)
        stage_half(A, Bt, lds + ((kt + 2) % NBUF) * TILEB, tid, m0, n0, (kt + 2) * BK, 1);
    if (PRE) {
        read_frags(lds, (kt + 1) % NBUF, 0, wm, wn, r15, q, afn, bfn);  // half0(t+1)
        asm volatile("s_waitcnt lgkmcnt(8)" ::: "memory");
    } else {
        asm volatile("s_waitcnt lgkmcnt(0)" ::: "memory");
    }
    __builtin_amdgcn_sched_barrier(0);
    mfma16(afc, bfc, acc);
}

__global__ __launch_bounds__(512, 2) void gemm_kernel(const unsigned short* __restrict__ A,
                                                      const unsigned short* __restrict__ Bt,
                                                      unsigned short* __restrict__ Y) {
    extern __shared__ char lds[];   // 3 * 48KB

    const int id  = blockIdx.x;
    const int xcd = id & 7;
    const int j   = id >> 3;                  // 0..31
    const int m0  = (xcd * 4 + (j >> 3)) * BM;
    const int n0  = (j & 7) * BN;

    const int tid  = threadIdx.x;
    const int lane = tid & 63;
    const int w    = tid >> 6;
    const int wm   = w >> 1;
    const int wn   = w & 1;
    const int r15  = lane & 15;
    const int q    = lane >> 4;

    f32x4 acc[4][4];
#pragma unroll
    for (int mf = 0; mf < 4; ++mf)
#pragma unroll
        for (int nf = 0; nf < 4; ++nf)
            acc[mf][nf] = (f32x4){0.f, 0.f, 0.f, 0.f};

    short8 aF0[4], bF0[4], aF1[4], bF1[4];

    // prologue: tiles 0,1 staged; half0(0) prefetched into F0
    stage_half(A, Bt, lds,         tid, m0, n0, 0,  0);
    stage_half(A, Bt, lds,         tid, m0, n0, 0,  1);
    stage_half(A, Bt, lds + TILEB, tid, m0, n0, BK, 0);
    stage_half(A, Bt, lds + TILEB, tid, m0, n0, BK, 1);
    asm volatile("s_waitcnt vmcnt(6)" ::: "memory");   // tile 0 landed
    __builtin_amdgcn_sched_barrier(0);
    __builtin_amdgcn_s_barrier();
    read_frags(lds, 0, 0, wm, wn, r15, q, aF0, bF0);

#pragma unroll 1
    for (int kt = 0; kt < 14; ++kt) {
        phase0<6, true>   (A, Bt, lds, tid, m0, n0, kt, wm, wn, r15, q, aF0, bF0, aF1, bF1, acc);
        phase1<3, true, true>(A, Bt, lds, tid, m0, n0, kt, wm, wn, r15, q, aF1, bF1, aF0, bF0, acc);
    }
    phase0<6, false>       (A, Bt, lds, tid, m0, n0, 14, wm, wn, r15, q, aF0, bF0, aF1, bF1, acc);
    phase1<0, false, true> (A, Bt, lds, tid, m0, n0, 14, wm, wn, r15, q, aF1, bF1, aF0, bF0, acc);
    phase0<0, false>       (A, Bt, lds, tid, m0, n0, 15, wm, wn, r15, q, aF0, bF0, aF1, bF1, acc);
    phase1<0, false, false>(A, Bt, lds, tid, m0, n0, 15, wm, wn, r15, q, aF1, bF1, aF0, bF0, acc);

    // write back: D layout col=lane&15, row=(lane>>4)*4+r
#pragma unroll
    for (int mf = 0; mf < 4; ++mf)
#pragma unroll
        for (int nf = 0; nf < 4; ++nf) {
            int col = n0 + wn * 64 + nf * 16 + r15;
#pragma unroll
            for (int r = 0; r < 4; ++r) {
                int row = m0 + wm * 64 + mf * 16 + q * 4 + r;
                Y[(size_t)row * NOUT + col] = f2bf(acc[mf][nf][r]);
            }
        }
}

// ---- epilogue: outer product + mean*sqrt(h) + rms_norm; 1 block/token,
// XCD-aligned: token t runs on XCD t>>10, where its Y rows were produced. ----
__global__ __launch_bounds__(256) void epilogue_kernel(const unsigned short* __restrict__ Y,
                                                       float* __restrict__ out) {
    __shared__ float ylds[1024];
    __shared__ float red[4];

    const int t = (blockIdx.x & 7) * 1024 + (blockIdx.x >> 3);
    const int tid = threadIdx.x;
    const unsigned short* yrow = Y + (size_t)t * NOUT;

    {
        uint2 raw = *(const uint2*)(yrow + tid * 4);
        ylds[tid * 4 + 0] = bf2f(raw.x & 0xffffu);
        ylds[tid * 4 + 1] = bf2f(raw.x >> 16);
        ylds[tid * 4 + 2] = bf2f(raw.y & 0xffffu);
        ylds[tid * 4 + 3] = bf2f(raw.y >> 16);
    }
    __syncthreads();

    const int jj = tid >> 3;
    const int k0 = (tid & 7) * 4;

    float o0 = 0.f, o1 = 0.f, o2 = 0.f, o3 = 0.f;
#pragma unroll
    for (int h = 0; h < NCB; ++h) {
        float a = ylds[h * 64 + jj];
        float4 bb = *(const float4*)&ylds[h * 64 + 32 + k0];
        o0 += a * bb.x; o1 += a * bb.y; o2 += a * bb.z; o3 += a * bb.w;
    }
    o0 *= 0.25f; o1 *= 0.25f; o2 *= 0.25f; o3 *= 0.25f;

    float ss = o0 * o0 + o1 * o1 + o2 * o2 + o3 * o3;
#pragma unroll
    for (int off = 32; off >= 1; off >>= 1)
        ss += __shfl_xor(ss, off, 64);

    const int lane = tid & 63, wv = tid >> 6;
    if (lane == 0) red[wv] = ss;
    __syncthreads();
    float tot = red[0] + red[1] + red[2] + red[3];
    float scale = rsqrtf(tot * (1.0f / 1024.0f) + 1e-12f);

    float4 o;
    o.x = o0 * scale; o.y = o1 * scale; o.z = o2 * scale; o.w = o3 * scale;
    *(float4*)(out + (size_t)t * 1024 + tid * 4) = o;
}

extern "C" void kernel_launch(void* const* d_in, const int* in_sizes, int n_in,
                              void* d_out, int out_size, void* d_ws, size_t ws_size,
                              hipStream_t stream) {
    const float* x   = (const float*)d_in[0];
    const float* wgt = (const float*)d_in[1];
    float* out = (float*)d_out;

    unsigned short* A  = (unsigned short*)d_ws;                        // 16 MB
    unsigned short* Bt = (unsigned short*)((char*)d_ws + (16u << 20)); //  2 MB
    unsigned short* Y  = (unsigned short*)((char*)d_ws + (18u << 20)); // 16 MB

    (void)hipFuncSetAttribute((const void*)gemm_kernel,
                              hipFuncAttributeMaxDynamicSharedMemorySize, NBUF * TILEB);

    conv_kernel<<<4096 + 512, 256, 0, stream>>>(x, wgt, A, Bt);
    gemm_kernel<<<(NTOK / BM) * (NOUT / BN), 512, NBUF * TILEB, stream>>>(A, Bt, Y);
    epilogue_kernel<<<NTOK, 256, 0, stream>>>(Y, out);
}

// Round 13
// 47.278 us; speedup vs baseline: 1.1587x; 1.0066x over previous
//
#include <hip/hip_runtime.h>
#include <hip/hip_bf16.h>

#define KDIM  1024
#define NOUT  1024
#define NTOK  8192
#define NCB   16
#define BM    256
#define BN    128
#define BK    64
#define TILEB 49152   // A 32KB + B 16KB per K-tile buffer
#define NBUF  3

typedef __attribute__((ext_vector_type(8))) short short8;
typedef __attribute__((ext_vector_type(4))) float f32x4;

__device__ static inline unsigned short f2bf(float f) {
    unsigned int u = __float_as_uint(f);
    return (unsigned short)((u + 0x7FFFu + ((u >> 16) & 1u)) >> 16);
}

__device__ static inline float bf2f(unsigned int h) {
    return __uint_as_float(h << 16);
}

__device__ static inline void async_copy16(const void* g, void* l) {
    __builtin_amdgcn_global_load_lds(
        (const __attribute__((address_space(1))) void*)g,
        (__attribute__((address_space(3))) void*)l, 16, 0, 0);
}

// ---- combined convert: x->A (XCD-aligned with gemm m-panels), W->Bt ----
__global__ __launch_bounds__(256) void conv_kernel(const float* __restrict__ x,
                                                   const float* __restrict__ W,
                                                   unsigned short* __restrict__ A,
                                                   unsigned short* __restrict__ Bt) {
    int b = blockIdx.x;
    if (b < 4096) {
        int bb = (b & 7) * 512 + (b >> 3);   // token-panel p -> XCD p (matches gemm)
        int u = bb * 256 + threadIdx.x;
        const float* src = x + (size_t)u * 8;
        float4 v0 = *(const float4*)(src);
        float4 v1 = *(const float4*)(src + 4);
        short8 o;
        o[0] = (short)f2bf(v0.x); o[1] = (short)f2bf(v0.y);
        o[2] = (short)f2bf(v0.z); o[3] = (short)f2bf(v0.w);
        o[4] = (short)f2bf(v1.x); o[5] = (short)f2bf(v1.y);
        o[6] = (short)f2bf(v1.z); o[7] = (short)f2bf(v1.w);
        *(short8*)(A + (size_t)u * 8) = o;
    } else {
        int u = (b - 4096) * 256 + threadIdx.x;
        int n  = u & (NOUT - 1);
        int k0 = (u >> 10) << 3;
        int h = n >> 6, o = n & 63;
        const float* src = W + (size_t)h * KDIM * 64 + o;
        short8 v;
#pragma unroll
        for (int j = 0; j < 8; ++j)
            v[j] = (short)f2bf(src[(size_t)(k0 + j) * 64]);
        *(short8*)(Bt + (size_t)n * KDIM + k0) = v;
    }
}

// ---- GEMM: BM=256 BN=128 BK=64, 512 thr (8 waves 4Mx2N), NBUF=3,
// 2-phase/K-tile, register frag prefetch 1 phase ahead, counted lgkm(8),
// minimal per-wave vmcnt (6/6 steady; audited vs FIFO retirement). ----

__device__ __forceinline__ void stage_half(const unsigned short* __restrict__ A,
                                           const unsigned short* __restrict__ Bt,
                                           char* lbase, int tid, int m0, int n0,
                                           int kel, int half) {
    unsigned short* Als = (unsigned short*)lbase;
    unsigned short* Bls = (unsigned short*)(lbase + 32768);
#pragma unroll
    for (int i = 0; i < 2; ++i) {
        int s = (half * 2 + i) * 512 + tid;
        int row = s >> 3;
        int cs = (s & 7) ^ (row & 7);
        async_copy16(A + (size_t)(m0 + row) * KDIM + kel + cs * 8, Als + s * 8);
    }
    {
        int s = half * 512 + tid;
        int row = s >> 3;
        int cs = (s & 7) ^ (row & 7);
        async_copy16(Bt + (size_t)(n0 + row) * KDIM + kel + cs * 8, Bls + s * 8);
    }
}

__device__ __forceinline__ void read_frags(const char* lds, int buf, int chunk,
                                           int wm, int wn, int r15, int q,
                                           short8 (&af)[4], short8 (&bf)[4]) {
    const unsigned short* Al = (const unsigned short*)(lds + buf * TILEB);
    const unsigned short* Bl = Al + 16384;
#pragma unroll
    for (int mf = 0; mf < 4; ++mf) {
        int row = wm * 64 + mf * 16 + r15;
        af[mf] = *(const short8*)(Al + row * 64 + (((chunk + q) ^ (row & 7)) << 3));
    }
#pragma unroll
    for (int nf = 0; nf < 4; ++nf) {
        int row = wn * 64 + nf * 16 + r15;
        bf[nf] = *(const short8*)(Bl + row * 64 + (((chunk + q) ^ (row & 7)) << 3));
    }
}

__device__ __forceinline__ void mfma16(short8 (&af)[4], short8 (&bf)[4], f32x4 (&acc)[4][4]) {
    __builtin_amdgcn_s_setprio(1);
#pragma unroll
    for (int mf = 0; mf < 4; ++mf)
#pragma unroll
        for (int nf = 0; nf < 4; ++nf)
            acc[mf][nf] = __builtin_amdgcn_mfma_f32_16x16x32_bf16(af[mf], bf[nf], acc[mf][nf], 0, 0, 0);
    __builtin_amdgcn_s_setprio(0);
}

// phase0(t): vmcnt(VM) [retire t-h1 stages]; bar; ds_read half1(t) -> Fn;
//            stage half0(t+2); lgkm(8); MFMA half0(t) from Fc.
template <int VM, bool STAGE>
__device__ __forceinline__ void phase0(const unsigned short* __restrict__ A,
                                       const unsigned short* __restrict__ Bt,
                                       char* lds, int tid, int m0, int n0, int kt,
                                       int wm, int wn, int r15, int q,
                                       short8 (&afc)[4], short8 (&bfc)[4],
                                       short8 (&afn)[4], short8 (&bfn)[4],
                                       f32x4 (&acc)[4][4]) {
    asm volatile("s_waitcnt vmcnt(%0)" :: "i"(VM) : "memory");
    __builtin_amdgcn_sched_barrier(0);
    __builtin_amdgcn_s_barrier();
    __builtin_amdgcn_sched_barrier(0);
    read_frags(lds, kt % NBUF, 4, wm, wn, r15, q, afn, bfn);   // half1(t)
    if (STAGE)
        stage_half(A, Bt, lds + ((kt + 2) % NBUF) * TILEB, tid, m0, n0, (kt + 2) * BK, 0);
    asm volatile("s_waitcnt lgkmcnt(8)" ::: "memory");
    __builtin_amdgcn_sched_barrier(0);
    mfma16(afc, bfc, acc);
}

// phase1(t): vmcnt(VM) [retire t+1-h0 stages]; bar; ds_read half0(t+1) -> Fn;
//            stage half1(t+2); lgkm(8 or 0); MFMA half1(t) from Fc.
template <int VM, bool STAGE, bool PRE>
__device__ __forceinline__ void phase1(const unsigned short* __restrict__ A,
                                       const unsigned short* __restrict__ Bt,
                                       char* lds, int tid, int m0, int n0, int kt,
                                       int wm, int wn, int r15, int q,
                                       short8 (&afc)[4], short8 (&bfc)[4],
                                       short8 (&afn)[4], short8 (&bfn)[4],
                                       f32x4 (&acc)[4][4]) {
    asm volatile("s_waitcnt vmcnt(%0)" :: "i"(VM) : "memory");
    __builtin_amdgcn_sched_barrier(0);
    __builtin_amdgcn_s_barrier();
    __builtin_amdgcn_sched_barrier(0);
    if (PRE)
        read_frags(lds, (kt + 1) % NBUF, 0, wm, wn, r15, q, afn, bfn);  // half0(t+1)
    if (STAGE)
        stage_half(A, Bt, lds + ((kt + 2) % NBUF) * TILEB, tid, m0, n0, (kt + 2) * BK, 1);
    if (PRE) {
        asm volatile("s_waitcnt lgkmcnt(8)" ::: "memory");
    } else {
        asm volatile("s_waitcnt lgkmcnt(0)" ::: "memory");
    }
    __builtin_amdgcn_sched_barrier(0);
    mfma16(afc, bfc, acc);
}

__global__ __launch_bounds__(512, 2) void gemm_kernel(const unsigned short* __restrict__ A,
                                                      const unsigned short* __restrict__ Bt,
                                                      unsigned short* __restrict__ Y) {
    extern __shared__ char lds[];   // 3 * 48KB

    const int id  = blockIdx.x;
    const int xcd = id & 7;
    const int j   = id >> 3;                  // 0..31
    const int m0  = (xcd * 4 + (j >> 3)) * BM;
    const int n0  = (j & 7) * BN;

    const int tid  = threadIdx.x;
    const int lane = tid & 63;
    const int w    = tid >> 6;
    const int wm   = w >> 1;
    const int wn   = w & 1;
    const int r15  = lane & 15;
    const int q    = lane >> 4;

    f32x4 acc[4][4];
#pragma unroll
    for (int mf = 0; mf < 4; ++mf)
#pragma unroll
        for (int nf = 0; nf < 4; ++nf)
            acc[mf][nf] = (f32x4){0.f, 0.f, 0.f, 0.f};

    short8 aF0[4], bF0[4], aF1[4], bF1[4];

    // prologue: tiles 0,1 staged; half0(0) prefetched into F0
    stage_half(A, Bt, lds,         tid, m0, n0, 0,  0);
    stage_half(A, Bt, lds,         tid, m0, n0, 0,  1);
    stage_half(A, Bt, lds + TILEB, tid, m0, n0, BK, 0);
    stage_half(A, Bt, lds + TILEB, tid, m0, n0, BK, 1);
    asm volatile("s_waitcnt vmcnt(6)" ::: "memory");   // tile 0 landed
    __builtin_amdgcn_sched_barrier(0);
    __builtin_amdgcn_s_barrier();
    read_frags(lds, 0, 0, wm, wn, r15, q, aF0, bF0);

#pragma unroll 1
    for (int kt = 0; kt < 14; ++kt) {
        phase0<6, true>      (A, Bt, lds, tid, m0, n0, kt, wm, wn, r15, q, aF0, bF0, aF1, bF1, acc);
        phase1<6, true, true>(A, Bt, lds, tid, m0, n0, kt, wm, wn, r15, q, aF1, bF1, aF0, bF0, acc);
    }
    phase0<6, false>       (A, Bt, lds, tid, m0, n0, 14, wm, wn, r15, q, aF0, bF0, aF1, bF1, acc);
    phase1<3, false, true> (A, Bt, lds, tid, m0, n0, 14, wm, wn, r15, q, aF1, bF1, aF0, bF0, acc);
    phase0<0, false>       (A, Bt, lds, tid, m0, n0, 15, wm, wn, r15, q, aF0, bF0, aF1, bF1, acc);
    phase1<0, false, false>(A, Bt, lds, tid, m0, n0, 15, wm, wn, r15, q, aF1, bF1, aF0, bF0, acc);

    // write back: D layout col=lane&15, row=(lane>>4)*4+r
#pragma unroll
    for (int mf = 0; mf < 4; ++mf)
#pragma unroll
        for (int nf = 0; nf < 4; ++nf) {
            int col = n0 + wn * 64 + nf * 16 + r15;
#pragma unroll
            for (int r = 0; r < 4; ++r) {
                int row = m0 + wm * 64 + mf * 16 + q * 4 + r;
                Y[(size_t)row * NOUT + col] = f2bf(acc[mf][nf][r]);
            }
        }
}

// ---- epilogue: outer product + mean*sqrt(h) + rms_norm; 1 block/token,
// XCD-aligned: token t runs on XCD t>>10, where its Y rows were produced. ----
__global__ __launch_bounds__(256) void epilogue_kernel(const unsigned short* __restrict__ Y,
                                                       float* __restrict__ out) {
    __shared__ float ylds[1024];
    __shared__ float red[4];

    const int t = (blockIdx.x & 7) * 1024 + (blockIdx.x >> 3);
    const int tid = threadIdx.x;
    const unsigned short* yrow = Y + (size_t)t * NOUT;

    {
        uint2 raw = *(const uint2*)(yrow + tid * 4);
        ylds[tid * 4 + 0] = bf2f(raw.x & 0xffffu);
        ylds[tid * 4 + 1] = bf2f(raw.x >> 16);
        ylds[tid * 4 + 2] = bf2f(raw.y & 0xffffu);
        ylds[tid * 4 + 3] = bf2f(raw.y >> 16);
    }
    __syncthreads();

    const int jj = tid >> 3;
    const int k0 = (tid & 7) * 4;

    float o0 = 0.f, o1 = 0.f, o2 = 0.f, o3 = 0.f;
#pragma unroll
    for (int h = 0; h < NCB; ++h) {
        float a = ylds[h * 64 + jj];
        float4 bb = *(const float4*)&ylds[h * 64 + 32 + k0];
        o0 += a * bb.x; o1 += a * bb.y; o2 += a * bb.z; o3 += a * bb.w;
    }
    o0 *= 0.25f; o1 *= 0.25f; o2 *= 0.25f; o3 *= 0.25f;

    float ss = o0 * o0 + o1 * o1 + o2 * o2 + o3 * o3;
#pragma unroll
    for (int off = 32; off >= 1; off >>= 1)
        ss += __shfl_xor(ss, off, 64);

    const int lane = tid & 63, wv = tid >> 6;
    if (lane == 0) red[wv] = ss;
    __syncthreads();
    float tot = red[0] + red[1] + red[2] + red[3];
    float scale = rsqrtf(tot * (1.0f / 1024.0f) + 1e-12f);

    float4 o;
    o.x = o0 * scale; o.y = o1 * scale; o.z = o2 * scale; o.w = o3 * scale;
    *(float4*)(out + (size_t)t * 1024 + tid * 4) = o;
}

extern "C" void kernel_launch(void* const* d_in, const int* in_sizes, int n_in,
                              void* d_out, int out_size, void* d_ws, size_t ws_size,
                              hipStream_t stream) {
    const float* x   = (const float*)d_in[0];
    const float* wgt = (const float*)d_in[1];
    float* out = (float*)d_out;

    unsigned short* A  = (unsigned short*)d_ws;                        // 16 MB
    unsigned short* Bt = (unsigned short*)((char*)d_ws + (16u << 20)); //  2 MB
    unsigned short* Y  = (unsigned short*)((char*)d_ws + (18u << 20)); // 16 MB

    (void)hipFuncSetAttribute((const void*)gemm_kernel,
                              hipFuncAttributeMaxDynamicSharedMemorySize, NBUF * TILEB);

    conv_kernel<<<4096 + 512, 256, 0, stream>>>(x, wgt, A, Bt);
    gemm_kernel<<<(NTOK / BM) * (NOUT / BN), 512, NBUF * TILEB, stream>>>(A, Bt, Y);
    epilogue_kernel<<<NTOK, 256, 0, stream>>>(Y, out);
}

// Round 14
// 46.611 us; speedup vs baseline: 1.1753x; 1.0143x over previous
//
#include <hip/hip_runtime.h>
#include <hip/hip_bf16.h>

#define KDIM  1024
#define NOUT  1024
#define NTOK  8192
#define NCB   16
#define BM    256
#define BN    128
#define BK    64
#define TILEB 49152   // A 32KB + B 16KB per K-tile buffer
#define NBUF  3

typedef __attribute__((ext_vector_type(8))) short short8;
typedef __attribute__((ext_vector_type(4))) float f32x4;

__device__ static inline unsigned short f2bf(float f) {
    unsigned int u = __float_as_uint(f);
    return (unsigned short)((u + 0x7FFFu + ((u >> 16) & 1u)) >> 16);
}

__device__ static inline float bf2f(unsigned int h) {
    return __uint_as_float(h << 16);
}

__device__ static inline void async_copy16(const void* g, void* l) {
    __builtin_amdgcn_global_load_lds(
        (const __attribute__((address_space(1))) void*)g,
        (__attribute__((address_space(3))) void*)l, 16, 0, 0);
}

// ---- combined convert: x->A (XCD-aligned with gemm m-panels), W->Bt ----
__global__ __launch_bounds__(256) void conv_kernel(const float* __restrict__ x,
                                                   const float* __restrict__ W,
                                                   unsigned short* __restrict__ A,
                                                   unsigned short* __restrict__ Bt) {
    int b = blockIdx.x;
    if (b < 4096) {
        int bb = (b & 7) * 512 + (b >> 3);   // token-panel p -> XCD p (matches gemm)
        int u = bb * 256 + threadIdx.x;
        const float* src = x + (size_t)u * 8;
        float4 v0 = *(const float4*)(src);
        float4 v1 = *(const float4*)(src + 4);
        short8 o;
        o[0] = (short)f2bf(v0.x); o[1] = (short)f2bf(v0.y);
        o[2] = (short)f2bf(v0.z); o[3] = (short)f2bf(v0.w);
        o[4] = (short)f2bf(v1.x); o[5] = (short)f2bf(v1.y);
        o[6] = (short)f2bf(v1.z); o[7] = (short)f2bf(v1.w);
        *(short8*)(A + (size_t)u * 8) = o;
    } else {
        int u = (b - 4096) * 256 + threadIdx.x;
        int n  = u & (NOUT - 1);
        int k0 = (u >> 10) << 3;
        int h = n >> 6, o = n & 63;
        const float* src = W + (size_t)h * KDIM * 64 + o;
        short8 v;
#pragma unroll
        for (int j = 0; j < 8; ++j)
            v[j] = (short)f2bf(src[(size_t)(k0 + j) * 64]);
        *(short8*)(Bt + (size_t)n * KDIM + k0) = v;
    }
}

// ---- GEMM: BM=256 BN=128 BK=64, 512 thr (8 waves 4Mx2N), NBUF=3.
// SINGLE barrier per K-tile: [vmcnt(6); bar; 16 ds_reads (h0+h1);
// stage tile t+2 (6 gloads); lgkm(8); 16 MFMA h0; lgkm(0); 16 MFMA h1].
// Safety: all reads of buffer t-1 retire via lgkm waits inside tile t-1,
// before any wave passes tile t's barrier -> stage(t+2)=(t-1)%NBUF is safe.

__device__ __forceinline__ void stage_tile(const unsigned short* __restrict__ A,
                                           const unsigned short* __restrict__ Bt,
                                           char* lbase, int tid, int m0, int n0, int kel) {
    unsigned short* Als = (unsigned short*)lbase;
    unsigned short* Bls = (unsigned short*)(lbase + 32768);
#pragma unroll
    for (int i = 0; i < 4; ++i) {
        int s = i * 512 + tid;
        int row = s >> 3;
        int cs = (s & 7) ^ (row & 7);
        async_copy16(A + (size_t)(m0 + row) * KDIM + kel + cs * 8, Als + s * 8);
    }
#pragma unroll
    for (int i = 0; i < 2; ++i) {
        int s = i * 512 + tid;
        int row = s >> 3;
        int cs = (s & 7) ^ (row & 7);
        async_copy16(Bt + (size_t)(n0 + row) * KDIM + kel + cs * 8, Bls + s * 8);
    }
}

__device__ __forceinline__ void read_frags(const char* lds, int buf, int chunk,
                                           int wm, int wn, int r15, int q,
                                           short8 (&af)[4], short8 (&bf)[4]) {
    const unsigned short* Al = (const unsigned short*)(lds + buf * TILEB);
    const unsigned short* Bl = Al + 16384;
#pragma unroll
    for (int mf = 0; mf < 4; ++mf) {
        int row = wm * 64 + mf * 16 + r15;
        af[mf] = *(const short8*)(Al + row * 64 + (((chunk + q) ^ (row & 7)) << 3));
    }
#pragma unroll
    for (int nf = 0; nf < 4; ++nf) {
        int row = wn * 64 + nf * 16 + r15;
        bf[nf] = *(const short8*)(Bl + row * 64 + (((chunk + q) ^ (row & 7)) << 3));
    }
}

__device__ __forceinline__ void mfma16(short8 (&af)[4], short8 (&bf)[4], f32x4 (&acc)[4][4]) {
    __builtin_amdgcn_s_setprio(1);
#pragma unroll
    for (int mf = 0; mf < 4; ++mf)
#pragma unroll
        for (int nf = 0; nf < 4; ++nf)
            acc[mf][nf] = __builtin_amdgcn_mfma_f32_16x16x32_bf16(af[mf], bf[nf], acc[mf][nf], 0, 0, 0);
    __builtin_amdgcn_s_setprio(0);
}

// one K-tile, single barrier
template <int VM, bool STAGE>
__device__ __forceinline__ void ktile(const unsigned short* __restrict__ A,
                                      const unsigned short* __restrict__ Bt,
                                      char* lds, int tid, int m0, int n0, int kt,
                                      int wm, int wn, int r15, int q,
                                      short8 (&aH0)[4], short8 (&bH0)[4],
                                      short8 (&aH1)[4], short8 (&bH1)[4],
                                      f32x4 (&acc)[4][4]) {
    asm volatile("s_waitcnt vmcnt(%0)" :: "i"(VM) : "memory");
    __builtin_amdgcn_sched_barrier(0);
    __builtin_amdgcn_s_barrier();
    __builtin_amdgcn_sched_barrier(0);
    read_frags(lds, kt % NBUF, 0, wm, wn, r15, q, aH0, bH0);
    read_frags(lds, kt % NBUF, 4, wm, wn, r15, q, aH1, bH1);
    if (STAGE)
        stage_tile(A, Bt, lds + ((kt + 2) % NBUF) * TILEB, tid, m0, n0, (kt + 2) * BK);
    asm volatile("s_waitcnt lgkmcnt(8)" ::: "memory");
    __builtin_amdgcn_sched_barrier(0);
    mfma16(aH0, bH0, acc);
    asm volatile("s_waitcnt lgkmcnt(0)" ::: "memory");
    __builtin_amdgcn_sched_barrier(0);
    mfma16(aH1, bH1, acc);
}

__global__ __launch_bounds__(512, 2) void gemm_kernel(const unsigned short* __restrict__ A,
                                                      const unsigned short* __restrict__ Bt,
                                                      unsigned short* __restrict__ Y) {
    extern __shared__ char lds[];   // 3 * 48KB

    const int id  = blockIdx.x;
    const int xcd = id & 7;
    const int j   = id >> 3;                  // 0..31
    const int m0  = (xcd * 4 + (j >> 3)) * BM;
    const int n0  = (j & 7) * BN;

    const int tid  = threadIdx.x;
    const int lane = tid & 63;
    const int w    = tid >> 6;
    const int wm   = w >> 1;
    const int wn   = w & 1;
    const int r15  = lane & 15;
    const int q    = lane >> 4;

    f32x4 acc[4][4];
#pragma unroll
    for (int mf = 0; mf < 4; ++mf)
#pragma unroll
        for (int nf = 0; nf < 4; ++nf)
            acc[mf][nf] = (f32x4){0.f, 0.f, 0.f, 0.f};

    short8 aH0[4], bH0[4], aH1[4], bH1[4];

    // prologue: tiles 0,1 in flight (12 loads/thread)
    stage_tile(A, Bt, lds,         tid, m0, n0, 0);
    stage_tile(A, Bt, lds + TILEB, tid, m0, n0, BK);

#pragma unroll 1
    for (int kt = 0; kt < 14; ++kt)
        ktile<6, true>(A, Bt, lds, tid, m0, n0, kt, wm, wn, r15, q, aH0, bH0, aH1, bH1, acc);
    ktile<6, false>(A, Bt, lds, tid, m0, n0, 14, wm, wn, r15, q, aH0, bH0, aH1, bH1, acc);
    ktile<0, false>(A, Bt, lds, tid, m0, n0, 15, wm, wn, r15, q, aH0, bH0, aH1, bH1, acc);

    // write back: D layout col=lane&15, row=(lane>>4)*4+r
#pragma unroll
    for (int mf = 0; mf < 4; ++mf)
#pragma unroll
        for (int nf = 0; nf < 4; ++nf) {
            int col = n0 + wn * 64 + nf * 16 + r15;
#pragma unroll
            for (int r = 0; r < 4; ++r) {
                int row = m0 + wm * 64 + mf * 16 + q * 4 + r;
                Y[(size_t)row * NOUT + col] = f2bf(acc[mf][nf][r]);
            }
        }
}

// ---- epilogue: outer product + mean*sqrt(h) + rms_norm; 1 block/token,
// XCD-aligned: token t runs on XCD t>>10, where its Y rows were produced. ----
__global__ __launch_bounds__(256) void epilogue_kernel(const unsigned short* __restrict__ Y,
                                                       float* __restrict__ out) {
    __shared__ float ylds[1024];
    __shared__ float red[4];

    const int t = (blockIdx.x & 7) * 1024 + (blockIdx.x >> 3);
    const int tid = threadIdx.x;
    const unsigned short* yrow = Y + (size_t)t * NOUT;

    {
        uint2 raw = *(const uint2*)(yrow + tid * 4);
        ylds[tid * 4 + 0] = bf2f(raw.x & 0xffffu);
        ylds[tid * 4 + 1] = bf2f(raw.x >> 16);
        ylds[tid * 4 + 2] = bf2f(raw.y & 0xffffu);
        ylds[tid * 4 + 3] = bf2f(raw.y >> 16);
    }
    __syncthreads();

    const int jj = tid >> 3;
    const int k0 = (tid & 7) * 4;

    float o0 = 0.f, o1 = 0.f, o2 = 0.f, o3 = 0.f;
#pragma unroll
    for (int h = 0; h < NCB; ++h) {
        float a = ylds[h * 64 + jj];
        float4 bb = *(const float4*)&ylds[h * 64 + 32 + k0];
        o0 += a * bb.x; o1 += a * bb.y; o2 += a * bb.z; o3 += a * bb.w;
    }
    o0 *= 0.25f; o1 *= 0.25f; o2 *= 0.25f; o3 *= 0.25f;

    float ss = o0 * o0 + o1 * o1 + o2 * o2 + o3 * o3;
#pragma unroll
    for (int off = 32; off >= 1; off >>= 1)
        ss += __shfl_xor(ss, off, 64);

    const int lane = tid & 63, wv = tid >> 6;
    if (lane == 0) red[wv] = ss;
    __syncthreads();
    float tot = red[0] + red[1] + red[2] + red[3];
    float scale = rsqrtf(tot * (1.0f / 1024.0f) + 1e-12f);

    float4 o;
    o.x = o0 * scale; o.y = o1 * scale; o.z = o2 * scale; o.w = o3 * scale;
    *(float4*)(out + (size_t)t * 1024 + tid * 4) = o;
}

extern "C" void kernel_launch(void* const* d_in, const int* in_sizes, int n_in,
                              void* d_out, int out_size, void* d_ws, size_t ws_size,
                              hipStream_t stream) {
    const float* x   = (const float*)d_in[0];
    const float* wgt = (const float*)d_in[1];
    float* out = (float*)d_out;

    unsigned short* A  = (unsigned short*)d_ws;                        // 16 MB
    unsigned short* Bt = (unsigned short*)((char*)d_ws + (16u << 20)); //  2 MB
    unsigned short* Y  = (unsigned short*)((char*)d_ws + (18u << 20)); // 16 MB

    (void)hipFuncSetAttribute((const void*)gemm_kernel,
                              hipFuncAttributeMaxDynamicSharedMemorySize, NBUF * TILEB);

    conv_kernel<<<4096 + 512, 256, 0, stream>>>(x, wgt, A, Bt);
    gemm_kernel<<<(NTOK / BM) * (NOUT / BN), 512, NBUF * TILEB, stream>>>(A, Bt, Y);
    epilogue_kernel<<<NTOK, 256, 0, stream>>>(Y, out);
}